// Round 12
// baseline (180.873 us; speedup 1.0000x reference)
//
#include <hip/hip_runtime.h>
#include <hip/hip_bf16.h>

#define NLEV 16
#define TSIZE (1u << 19)
#define TMASK ((1u << 19) - 1u)
#define P1 2654435761u
#define P2 805459861u
#define FP8_SCALE 8192.0f
#define FP8_INV (1.0f / 8192.0f)

// Dense-grid tables for levels 0..4 (res 16,23,33,48,70): CDIM = R+2 cells/dim.
#define NDENSE 5
#define DTOTAL 562580   // 18^3 + 25^3 + 35^3 + 50^3 + 72^3
#define CONV_BLOCKS 2048

typedef __attribute__((ext_vector_type(8))) short short8;
typedef __attribute__((ext_vector_type(4))) float f32x4;

// floor(16 * b^l), b = 256^(1/15) — matches numpy float64 computation.
__device__ __constant__ float c_res[NLEV] = {
    16.f, 23.f, 33.f, 48.f, 70.f, 101.f, 147.f, 212.f,
    307.f, 445.f, 645.f, 933.f, 1351.f, 1955.f, 2830.f, 4096.f};

__device__ __constant__ int c_cdim[NDENSE] = {18, 25, 35, 50, 72};
__device__ __constant__ int c_doff[NDENSE] = {0, 5832, 21457, 64332, 189332};

__device__ __forceinline__ short bf16_bits(float v) {
    __hip_bfloat16 h = __float2bfloat16(v);
    unsigned short us;
    __builtin_memcpy(&us, &h, 2);
    return (short)us;
}

__device__ __forceinline__ unsigned pack2_bf16(float lo, float hi) {
    unsigned a = (unsigned short)bf16_bits(lo);
    unsigned b = (unsigned short)bf16_bits(hi);
    return a | (b << 16);
}

// ---------------- Phase 0 (merged): convert fp8 pairs + build dense --------
// Blocks [0, CONV_BLOCKS): fp8 pair table for levels 5..15 (grid-stride).
// Blocks [CONV_BLOCKS, ...): dense 16B/cell tables for levels 0..4 (one
// thread per cell, 8 hash-gathers each — reproduces collisions exactly).
__global__ __launch_bounds__(256) void prep_kernel(
    const float2* __restrict__ table, unsigned* __restrict__ pq,
    uint4* __restrict__ dense, int conv_start, int conv_total)
{
    int b = blockIdx.x;
    if (b < CONV_BLOCKS) {
        for (int i = b * 256 + threadIdx.x; i < conv_total; i += CONV_BLOCKS * 256) {
            int ig = conv_start + i;
            float2 e = table[ig];
            float nx = __shfl_xor(e.x, 1);   // entry[ig^1] from partner lane
            float ny = __shfl_xor(e.y, 1);
            unsigned lo = __builtin_amdgcn_cvt_pk_fp8_f32(e.x * FP8_SCALE, e.y * FP8_SCALE, 0u, false);
            unsigned all4 = __builtin_amdgcn_cvt_pk_fp8_f32(nx * FP8_SCALE, ny * FP8_SCALE, lo, true);
            pq[ig] = all4;
        }
        return;
    }

    int t = (b - CONV_BLOCKS) * 256 + threadIdx.x;
    if (t >= DTOTAL) return;
    int l = 4;
    if (t < c_doff[1]) l = 0;
    else if (t < c_doff[2]) l = 1;
    else if (t < c_doff[3]) l = 2;
    else if (t < c_doff[4]) l = 3;
    int rel = t - c_doff[l];
    int dim = c_cdim[l];
    int ix = rel % dim;
    int rem = rel / dim;
    int iy = rem % dim;
    int iz = rem / dim;
    const float2* tl = table + (size_t)l * TSIZE;

    float2 v[8];
#pragma unroll
    for (int e = 0; e < 8; ++e) {
        unsigned cx = (unsigned)(ix + (e & 1));
        unsigned cy = (unsigned)(iy + ((e >> 1) & 1));
        unsigned cz = (unsigned)(iz + (e >> 2));
        unsigned h = (cx ^ (cy * P1) ^ (cz * P2)) & TMASK;
        v[e] = tl[h];
    }
    unsigned w[4];
#pragma unroll
    for (int d = 0; d < 4; ++d) {
        unsigned lo = __builtin_amdgcn_cvt_pk_fp8_f32(v[2 * d].x * FP8_SCALE,
                                                      v[2 * d].y * FP8_SCALE, 0u, false);
        w[d] = __builtin_amdgcn_cvt_pk_fp8_f32(v[2 * d + 1].x * FP8_SCALE,
                                               v[2 * d + 1].y * FP8_SCALE, lo, true);
    }
    dense[t] = make_uint4(w[0], w[1], w[2], w[3]);
}

// ---------------- Phase 1 (merged): hash levels 5..15 + dense levels 0..4 --
// 22 hash half-level units on the 8-slot XCD-pinned layout (slots 0-5: 3
// units, slots 6-7: 2 units + their third-unit blocks re-routed to early
// dense work). Remaining dense blocks appended after the hash region.
__global__ __launch_bounds__(256) void encode_kernel(
    const float* __restrict__ pos,      // [N,3]
    const unsigned* __restrict__ pq,    // [16][2^19] fp8 pair (5..15 filled)
    const uint4* __restrict__ dense,    // dense cell tables, levels 0..4
    __hip_bfloat162* __restrict__ feat, // [16][N] level-major
    int n, unsigned halfn, unsigned nbh, unsigned bpl)
{
    unsigned b = blockIdx.x;
    unsigned H = 24u * nbh;
    const int tid = threadIdx.x;

    unsigned db = 0xFFFFFFFFu;
    if (b >= H) {
        db = (b - H) + 2u * nbh;         // appended dense blocks
    } else {
        unsigned slot = b & 7u;
        unsigned jj = b >> 3u;
        unsigned ur = jj / nbh;          // 0..2
        unsigned pb = jj % nbh;
        unsigned u = slot + 8u * ur;     // 0..23
        if (u >= 22u) {
            db = (u - 22u) * nbh + pb;   // first 2*nbh dense blocks
        } else {
            // ---- hash path: level l = 5 + u/2, half = u&1 ----
            unsigned l = 5u + (u >> 1);
            unsigned half = u & 1u;
            const float r = c_res[l];
            const unsigned* tl = pq + (size_t)l * TSIZE;
            const int base = (int)(half * halfn + pb * 1024u);

            unsigned gq[16];
            float wxl[4], wyl[4], wzl[4];
            unsigned sll[4];
            int idx[4];

#pragma unroll
            for (int k = 0; k < 4; ++k) {
                int i = base + 256 * k + tid;
                if (i >= n) i = n - 1;   // clamp: harmless duplicate work
                idx[k] = i;
                float x = (pos[3 * i + 0] + 1.f) * 0.5f;
                float y = (pos[3 * i + 1] + 1.f) * 0.5f;
                float z = (pos[3 * i + 2] + 1.f) * 0.5f;
                float sx = x * r, sy = y * r, sz = z * r;
                float fx = floorf(sx), fy = floorf(sy), fz = floorf(sz);
                wxl[k] = sx - fx; wyl[k] = sy - fy; wzl[k] = sz - fz;
                unsigned ix = (unsigned)fx, iy = (unsigned)fy, iz = (unsigned)fz;
                unsigned hy0 = iy * P1, hy1 = hy0 + P1;
                unsigned hz0 = iz * P2, hz1 = hz0 + P2;
                unsigned a00 = hy0 ^ hz0, a10 = hy1 ^ hz0;
                unsigned a01 = hy0 ^ hz1, a11 = hy1 ^ hz1;
                unsigned sel = ix & 1u;
                unsigned jx = ix + sel;
                sll[k] = sel;
                gq[4 * k + 0] = tl[(jx ^ a00) & TMASK];
                gq[4 * k + 1] = tl[(jx ^ a10) & TMASK];
                gq[4 * k + 2] = tl[(jx ^ a01) & TMASK];
                gq[4 * k + 3] = tl[(jx ^ a11) & TMASK];
            }

#pragma unroll
            for (int k = 0; k < 4; ++k) {
                float wx = wxl[k], wy = wyl[k], wz = wzl[k];
                bool s = sll[k] != 0u;
                unsigned u00 = gq[4 * k + 0], u10 = gq[4 * k + 1];
                unsigned u01 = gq[4 * k + 2], u11 = gq[4 * k + 3];

                float a0_00 = __builtin_amdgcn_cvt_f32_fp8(u00, 0), a1_00 = __builtin_amdgcn_cvt_f32_fp8(u00, 1);
                float b0_00 = __builtin_amdgcn_cvt_f32_fp8(u00, 2), b1_00 = __builtin_amdgcn_cvt_f32_fp8(u00, 3);
                float a0_10 = __builtin_amdgcn_cvt_f32_fp8(u10, 0), a1_10 = __builtin_amdgcn_cvt_f32_fp8(u10, 1);
                float b0_10 = __builtin_amdgcn_cvt_f32_fp8(u10, 2), b1_10 = __builtin_amdgcn_cvt_f32_fp8(u10, 3);
                float a0_01 = __builtin_amdgcn_cvt_f32_fp8(u01, 0), a1_01 = __builtin_amdgcn_cvt_f32_fp8(u01, 1);
                float b0_01 = __builtin_amdgcn_cvt_f32_fp8(u01, 2), b1_01 = __builtin_amdgcn_cvt_f32_fp8(u01, 3);
                float a0_11 = __builtin_amdgcn_cvt_f32_fp8(u11, 0), a1_11 = __builtin_amdgcn_cvt_f32_fp8(u11, 1);
                float b0_11 = __builtin_amdgcn_cvt_f32_fp8(u11, 2), b1_11 = __builtin_amdgcn_cvt_f32_fp8(u11, 3);

                float lo0_00 = s ? b0_00 : a0_00, hi0_00 = s ? a0_00 : b0_00;
                float lo1_00 = s ? b1_00 : a1_00, hi1_00 = s ? a1_00 : b1_00;
                float lo0_10 = s ? b0_10 : a0_10, hi0_10 = s ? a0_10 : b0_10;
                float lo1_10 = s ? b1_10 : a1_10, hi1_10 = s ? a1_10 : b1_10;
                float lo0_01 = s ? b0_01 : a0_01, hi0_01 = s ? a0_01 : b0_01;
                float lo1_01 = s ? b1_01 : a1_01, hi1_01 = s ? a1_01 : b1_01;
                float lo0_11 = s ? b0_11 : a0_11, hi0_11 = s ? a0_11 : b0_11;
                float lo1_11 = s ? b1_11 : a1_11, hi1_11 = s ? a1_11 : b1_11;

                float ux = 1.f - wx, uy = 1.f - wy, uz = 1.f - wz;
                float w000 = ux * uy * uz, w100 = wx * uy * uz;
                float w010 = ux * wy * uz, w110 = wx * wy * uz;
                float w001 = ux * uy * wz, w101 = wx * uy * wz;
                float w011 = ux * wy * wz, w111 = wx * wy * wz;

                float f0 = lo0_00 * w000 + hi0_00 * w100 + lo0_10 * w010 + hi0_10 * w110 +
                           lo0_01 * w001 + hi0_01 * w101 + lo0_11 * w011 + hi0_11 * w111;
                float f1 = lo1_00 * w000 + hi1_00 * w100 + lo1_10 * w010 + hi1_10 * w110 +
                           lo1_01 * w001 + hi1_01 * w101 + lo1_11 * w011 + hi1_11 * w111;

                __hip_bfloat162 v;
                v.x = __float2bfloat16(f0 * FP8_INV);
                v.y = __float2bfloat16(f1 * FP8_INV);
                feat[(size_t)l * n + idx[k]] = v;
            }
            return;
        }
    }

    // ---- dense path (levels 0..4, 1 request per point) ----
    int l = (int)(db / bpl);
    int i = (int)((db % bpl) * 256u) + tid;
    if (i >= n) return;

    float x = (pos[3 * i + 0] + 1.f) * 0.5f;
    float y = (pos[3 * i + 1] + 1.f) * 0.5f;
    float z = (pos[3 * i + 2] + 1.f) * 0.5f;
    float r = c_res[l];
    float sx = x * r, sy = y * r, sz = z * r;
    float fx = floorf(sx), fy = floorf(sy), fz = floorf(sz);
    float wx = sx - fx, wy = sy - fy, wz = sz - fz;
    int dim = c_cdim[l];
    unsigned ix = (unsigned)fx, iy = (unsigned)fy, iz = (unsigned)fz;
    ix = ix > (unsigned)(dim - 2) ? (unsigned)(dim - 2) : ix;
    iy = iy > (unsigned)(dim - 2) ? (unsigned)(dim - 2) : iy;
    iz = iz > (unsigned)(dim - 2) ? (unsigned)(dim - 2) : iz;

    uint4 wv = dense[(size_t)c_doff[l] + ((size_t)iz * dim + iy) * dim + ix];
    unsigned dw[4] = {wv.x, wv.y, wv.z, wv.w};

    float ux = 1.f - wx, uy = 1.f - wy, uz = 1.f - wz;
    float wyz[4] = {uy * uz, wy * uz, uy * wz, wy * wz};   // d = dy + 2*dz

    float f0 = 0.f, f1 = 0.f;
#pragma unroll
    for (int d = 0; d < 4; ++d) {
        unsigned word = dw[d];
        float we = ux * wyz[d];          // entry 2d   (dx=0): bytes 0,1
        float wo = wx * wyz[d];          // entry 2d+1 (dx=1): bytes 2,3
        f0 += __builtin_amdgcn_cvt_f32_fp8(word, 0) * we
            + __builtin_amdgcn_cvt_f32_fp8(word, 2) * wo;
        f1 += __builtin_amdgcn_cvt_f32_fp8(word, 1) * we
            + __builtin_amdgcn_cvt_f32_fp8(word, 3) * wo;
    }

    __hip_bfloat162 v;
    v.x = __float2bfloat16(f0 * FP8_INV);
    v.y = __float2bfloat16(f1 * FP8_INV);
    feat[(size_t)l * n + i] = v;
}

// ---------------- Phase 1 fallback: fp32 table, 8 gathers, 16 levels -------
__global__ __launch_bounds__(256) void hash_encode_kernel(
    const float* __restrict__ pos,
    const float* __restrict__ table,
    __hip_bfloat162* __restrict__ feat,
    int n, unsigned bpl)
{
    unsigned b = blockIdx.x;
    unsigned slot = b & 7u;
    unsigned jj = b >> 3u;
    unsigned l = slot + 8u * (jj / bpl);
    unsigned pblk = jj % bpl;
    int i = (int)(pblk * 256u + threadIdx.x);
    if (i >= n) return;

    float x = (pos[3 * i + 0] + 1.f) * 0.5f;
    float y = (pos[3 * i + 1] + 1.f) * 0.5f;
    float z = (pos[3 * i + 2] + 1.f) * 0.5f;

    float r = c_res[l];
    float sx = x * r, sy = y * r, sz = z * r;
    float fx = floorf(sx), fy = floorf(sy), fz = floorf(sz);
    float wx = sx - fx, wy = sy - fy, wz = sz - fz;
    unsigned ix = (unsigned)fx, iy = (unsigned)fy, iz = (unsigned)fz;
    unsigned hy0 = iy * P1, hy1 = hy0 + P1;
    unsigned hz0 = iz * P2, hz1 = hz0 + P2;
    unsigned a00 = hy0 ^ hz0, a10 = hy1 ^ hz0;
    unsigned a01 = hy0 ^ hz1, a11 = hy1 ^ hz1;
    unsigned ix1 = ix + 1u;

    const float2* tl = (const float2*)table + (size_t)l * TSIZE;
    float2 e000 = tl[(ix  ^ a00) & TMASK];
    float2 e100 = tl[(ix1 ^ a00) & TMASK];
    float2 e010 = tl[(ix  ^ a10) & TMASK];
    float2 e110 = tl[(ix1 ^ a10) & TMASK];
    float2 e001 = tl[(ix  ^ a01) & TMASK];
    float2 e101 = tl[(ix1 ^ a01) & TMASK];
    float2 e011 = tl[(ix  ^ a11) & TMASK];
    float2 e111 = tl[(ix1 ^ a11) & TMASK];

    float ux = 1.f - wx, uy = 1.f - wy, uz = 1.f - wz;
    float w000 = ux * uy * uz, w100 = wx * uy * uz;
    float w010 = ux * wy * uz, w110 = wx * wy * uz;
    float w001 = ux * uy * wz, w101 = wx * uy * wz;
    float w011 = ux * wy * wz, w111 = wx * wy * wz;

    float f0 = e000.x * w000 + e100.x * w100 + e010.x * w010 + e110.x * w110 +
               e001.x * w001 + e101.x * w101 + e011.x * w011 + e111.x * w111;
    float f1 = e000.y * w000 + e100.y * w100 + e010.y * w010 + e110.y * w110 +
               e001.y * w001 + e101.y * w101 + e011.y * w011 + e111.y * w111;

    __hip_bfloat162 v;
    v.x = __float2bfloat16(f0);
    v.y = __float2bfloat16(f1);
    feat[(size_t)l * n + i] = v;
}

// ---------------- Phase 2: bf16 MFMA MLP (batched feat loads) --------------
__device__ __forceinline__ void store_H(char* hrow, int g, int swz, f32x4* acc) {
#pragma unroll
    for (int mt = 0; mt < 4; ++mt) {
        float v0 = fmaxf(acc[mt][0], 0.f), v1 = fmaxf(acc[mt][1], 0.f);
        float v2 = fmaxf(acc[mt][2], 0.f), v3 = fmaxf(acc[mt][3], 0.f);
        unsigned lo = pack2_bf16(v0, v1);
        unsigned hi = pack2_bf16(v2, v3);
        int blk = (2 * mt + (g >> 1)) ^ swz;
        *(uint2*)(hrow + blk * 16 + (g & 1) * 8) = make_uint2(lo, hi);
    }
}

__global__ __launch_bounds__(256) void mlp_mfma_kernel(
    const float* __restrict__ pos,
    const unsigned* __restrict__ feat,  // [16][n] u32 = bf16x2
    const float* __restrict__ W0,
    const float* __restrict__ W1,
    const float* __restrict__ W2,
    const float* __restrict__ W3,
    float* __restrict__ out, int n, int nchunks)
{
    __shared__ char hlds[4 * 16 * 128];
    const int tid  = threadIdx.x;
    const int w    = tid >> 6;
    const int lane = tid & 63;
    const int g    = lane >> 4;
    const int p    = lane & 15;
    char* hrow = hlds + w * (16 * 128) + p * 128;
    const int swz = p & 7;

    short8 a0[4], a1[4][2], a2[4][2], a3[2];
#pragma unroll
    for (int mt = 0; mt < 4; ++mt)
#pragma unroll
        for (int jj = 0; jj < 8; ++jj)
            a0[mt][jj] = bf16_bits(W0[(8 * g + jj) * 64 + 16 * mt + p]);
#pragma unroll
    for (int mt = 0; mt < 4; ++mt)
#pragma unroll
        for (int kt = 0; kt < 2; ++kt)
#pragma unroll
            for (int jj = 0; jj < 8; ++jj) {
                a1[mt][kt][jj] = bf16_bits(W1[(32 * kt + 8 * g + jj) * 64 + 16 * mt + p]);
                a2[mt][kt][jj] = bf16_bits(W2[(32 * kt + 8 * g + jj) * 64 + 16 * mt + p]);
            }
#pragma unroll
    for (int kt = 0; kt < 2; ++kt)
#pragma unroll
        for (int jj = 0; jj < 8; ++jj)
            a3[kt][jj] = (p < 4) ? bf16_bits(W3[(32 * kt + 8 * g + jj) * 4 + p]) : (short)0;

    const f32x4 zf = {0.f, 0.f, 0.f, 0.f};

    for (int c = blockIdx.x; c < nchunks; c += gridDim.x) {
        const int base = c * 256 + w * 64;

        // batch all 16 feat loads (4 t-tiles x 4 planes) before any compute
        unsigned buall[4][4];
#pragma unroll
        for (int t = 0; t < 4; ++t) {
            int ptg = base + t * 16 + p;
            int ptc = ptg < n ? ptg : n - 1;
#pragma unroll
            for (int m = 0; m < 4; ++m)
                buall[t][m] = feat[(size_t)(4 * g + m) * (size_t)n + ptc];
        }

#pragma unroll
        for (int t = 0; t < 4; ++t) {
            const int ptg = base + t * 16 + p;

            union { unsigned u[4]; short8 s; } bu;
#pragma unroll
            for (int m = 0; m < 4; ++m) bu.u[m] = buall[t][m];

            f32x4 acc[4];
#pragma unroll
            for (int mt = 0; mt < 4; ++mt)
                acc[mt] = __builtin_amdgcn_mfma_f32_16x16x32_bf16(a0[mt], bu.s, zf, 0, 0, 0);

            store_H(hrow, g, swz, acc);
            short8 b0 = *(const short8*)(hrow + ((g ^ swz) << 4));
            short8 b1 = *(const short8*)(hrow + (((4 + g) ^ swz) << 4));

#pragma unroll
            for (int mt = 0; mt < 4; ++mt) {
                acc[mt] = __builtin_amdgcn_mfma_f32_16x16x32_bf16(a1[mt][0], b0, zf, 0, 0, 0);
                acc[mt] = __builtin_amdgcn_mfma_f32_16x16x32_bf16(a1[mt][1], b1, acc[mt], 0, 0, 0);
            }

            store_H(hrow, g, swz, acc);
            b0 = *(const short8*)(hrow + ((g ^ swz) << 4));
            b1 = *(const short8*)(hrow + (((4 + g) ^ swz) << 4));

#pragma unroll
            for (int mt = 0; mt < 4; ++mt) {
                acc[mt] = __builtin_amdgcn_mfma_f32_16x16x32_bf16(a2[mt][0], b0, zf, 0, 0, 0);
                acc[mt] = __builtin_amdgcn_mfma_f32_16x16x32_bf16(a2[mt][1], b1, acc[mt], 0, 0, 0);
            }

            store_H(hrow, g, swz, acc);
            b0 = *(const short8*)(hrow + ((g ^ swz) << 4));
            b1 = *(const short8*)(hrow + (((4 + g) ^ swz) << 4));

            f32x4 o = __builtin_amdgcn_mfma_f32_16x16x32_bf16(a3[0], b0, zf, 0, 0, 0);
            o = __builtin_amdgcn_mfma_f32_16x16x32_bf16(a3[1], b1, o, 0, 0, 0);

            if (g == 0 && ptg < n) {
                float px = pos[3 * ptg + 0];
                float py = pos[3 * ptg + 1];
                float pz = pos[3 * ptg + 2];
                float xx = (px + 1.f) * 0.5f;
                float yy = (py + 1.f) * 0.5f;
                float zz = (pz + 1.f) * 0.5f;
                bool sel = (xx > 0.f) && (xx < 1.f) && (yy > 0.f) && (yy < 1.f) &&
                           (zz > 0.f) && (zz < 1.f);
                out[3 * (size_t)ptg + 0] = 1.f / (1.f + expf(-o[0]));
                out[3 * (size_t)ptg + 1] = 1.f / (1.f + expf(-o[1]));
                out[3 * (size_t)ptg + 2] = 1.f / (1.f + expf(-o[2]));
                out[3 * (size_t)n + ptg] = expf(o[3] - 1.f) * (sel ? 1.f : 0.f);
            }
        }
    }
}

// ---------------- Fallback: fused scalar kernel (if ws too small) ----------
__global__ __launch_bounds__(256) void hashgrid_fused_kernel(
    const float* __restrict__ pos, const float* __restrict__ table,
    const float* __restrict__ W0, const float* __restrict__ W1,
    const float* __restrict__ W2, const float* __restrict__ W3,
    float* __restrict__ out, int n)
{
    int id = blockIdx.x * 256 + threadIdx.x;
    int i = id < n ? id : n - 1;

    float x = (pos[3 * i + 0] + 1.f) * 0.5f;
    float y = (pos[3 * i + 1] + 1.f) * 0.5f;
    float z = (pos[3 * i + 2] + 1.f) * 0.5f;
    bool sel = (x > 0.f) && (x < 1.f) && (y > 0.f) && (y < 1.f) &&
               (z > 0.f) && (z < 1.f);

    float h0[64];
#pragma unroll
    for (int j = 0; j < 64; ++j) h0[j] = 0.f;

    const float2* tb = (const float2*)table;
#pragma unroll
    for (int l = 0; l < NLEV; ++l) {
        float r = c_res[l];
        float sx = x * r, sy = y * r, sz = z * r;
        float fx = floorf(sx), fy = floorf(sy), fz = floorf(sz);
        float wx = sx - fx, wy = sy - fy, wz = sz - fz;
        unsigned ix = (unsigned)fx, iy = (unsigned)fy, iz = (unsigned)fz;
        unsigned hy0 = iy * P1, hy1 = hy0 + P1;
        unsigned hz0 = iz * P2, hz1 = hz0 + P2;
        unsigned a00 = hy0 ^ hz0, a10 = hy1 ^ hz0;
        unsigned a01 = hy0 ^ hz1, a11 = hy1 ^ hz1;
        unsigned ix1 = ix + 1u;
        const float2* tl = tb + (size_t)l * TSIZE;
        float2 e000 = tl[(ix  ^ a00) & TMASK];
        float2 e100 = tl[(ix1 ^ a00) & TMASK];
        float2 e010 = tl[(ix  ^ a10) & TMASK];
        float2 e110 = tl[(ix1 ^ a10) & TMASK];
        float2 e001 = tl[(ix  ^ a01) & TMASK];
        float2 e101 = tl[(ix1 ^ a01) & TMASK];
        float2 e011 = tl[(ix  ^ a11) & TMASK];
        float2 e111 = tl[(ix1 ^ a11) & TMASK];

        float ux = 1.f - wx, uy = 1.f - wy, uz = 1.f - wz;
        float w000 = ux * uy * uz, w100 = wx * uy * uz;
        float w010 = ux * wy * uz, w110 = wx * wy * uz;
        float w001 = ux * uy * wz, w101 = wx * uy * wz;
        float w011 = ux * wy * wz, w111 = wx * wy * wz;

        float f0 = e000.x * w000 + e100.x * w100 + e010.x * w010 + e110.x * w110 +
                   e001.x * w001 + e101.x * w101 + e011.x * w011 + e111.x * w111;
        float f1 = e000.y * w000 + e100.y * w100 + e010.y * w010 + e110.y * w110 +
                   e001.y * w001 + e101.y * w101 + e011.y * w011 + e111.y * w111;

        const float* w0a = W0 + (2 * l) * 64;
        const float* w0b = W0 + (2 * l + 1) * 64;
#pragma unroll
        for (int j = 0; j < 64; ++j)
            h0[j] = fmaf(f0, w0a[j], fmaf(f1, w0b[j], h0[j]));
    }
#pragma unroll
    for (int j = 0; j < 64; ++j) h0[j] = fmaxf(h0[j], 0.f);

    float h1[64];
#pragma unroll
    for (int j = 0; j < 64; ++j) h1[j] = 0.f;
#pragma unroll
    for (int k = 0; k < 64; ++k) {
        float v = h0[k];
        const float* wr = W1 + k * 64;
#pragma unroll
        for (int j = 0; j < 64; ++j) h1[j] = fmaf(v, wr[j], h1[j]);
    }
#pragma unroll
    for (int j = 0; j < 64; ++j) h1[j] = fmaxf(h1[j], 0.f);

#pragma unroll
    for (int j = 0; j < 64; ++j) h0[j] = 0.f;
#pragma unroll
    for (int k = 0; k < 64; ++k) {
        float v = h1[k];
        const float* wr = W2 + k * 64;
#pragma unroll
        for (int j = 0; j < 64; ++j) h0[j] = fmaf(v, wr[j], h0[j]);
    }
#pragma unroll
    for (int j = 0; j < 64; ++j) h0[j] = fmaxf(h0[j], 0.f);

    float o0 = 0.f, o1 = 0.f, o2 = 0.f, o3 = 0.f;
#pragma unroll
    for (int k = 0; k < 64; ++k) {
        float v = h0[k];
        const float* wr = W3 + k * 4;
        o0 = fmaf(v, wr[0], o0);
        o1 = fmaf(v, wr[1], o1);
        o2 = fmaf(v, wr[2], o2);
        o3 = fmaf(v, wr[3], o3);
    }

    if (id < n) {
        float r = 1.f / (1.f + expf(-o0));
        float g = 1.f / (1.f + expf(-o1));
        float b = 1.f / (1.f + expf(-o2));
        float d = expf(o3 - 1.f) * (sel ? 1.f : 0.f);
        out[3 * (size_t)i + 0] = r;
        out[3 * (size_t)i + 1] = g;
        out[3 * (size_t)i + 2] = b;
        out[3 * (size_t)n + i] = d;
    }
}

extern "C" void kernel_launch(void* const* d_in, const int* in_sizes, int n_in,
                              void* d_out, int out_size, void* d_ws, size_t ws_size,
                              hipStream_t stream) {
    const float* pos   = (const float*)d_in[0];
    const float* table = (const float*)d_in[1];
    const float* W0    = (const float*)d_in[2];
    const float* W1    = (const float*)d_in[3];
    const float* W2    = (const float*)d_in[4];
    const float* W3    = (const float*)d_in[5];
    float* out = (float*)d_out;
    int n = in_sizes[0] / 3;
    unsigned bpl = (unsigned)((n + 255) / 256);
    unsigned halfn = (unsigned)((n + 1) / 2);
    unsigned nbh = (halfn + 1023) / 1024;
    int nchunks = (n + 255) / 256;
    int mblocks = nchunks < 2048 ? nchunks : 2048;

    size_t pq_bytes    = (size_t)NLEV * TSIZE * sizeof(unsigned);  // 33.5 MB
    size_t dense_bytes = (size_t)DTOTAL * sizeof(uint4);           // 9.0 MB
    size_t feat_bytes  = (size_t)NLEV * n * sizeof(__hip_bfloat162);

    if (ws_size >= pq_bytes + dense_bytes + feat_bytes) {
        unsigned* pq = (unsigned*)d_ws;
        uint4* dense = (uint4*)((char*)d_ws + pq_bytes);
        __hip_bfloat162* feat = (__hip_bfloat162*)((char*)d_ws + pq_bytes + dense_bytes);

        int prep_blocks = CONV_BLOCKS + (DTOTAL + 255) / 256;
        hipLaunchKernelGGL(prep_kernel, dim3(prep_blocks), dim3(256), 0, stream,
                           (const float2*)table, pq, dense,
                           5 * (int)TSIZE, 11 * (int)TSIZE);
        // dense blocks total = NDENSE*bpl; first 2*nbh run inside the hash
        // region (slots 6,7 third unit), remainder appended after H = 24*nbh.
        unsigned dense_total = NDENSE * bpl;
        unsigned appended = dense_total > 2u * nbh ? dense_total - 2u * nbh : 0u;
        unsigned enc_blocks = 24u * nbh + appended;
        hipLaunchKernelGGL(encode_kernel, dim3(enc_blocks), dim3(256), 0, stream,
                           pos, pq, dense, feat, n, halfn, nbh, bpl);
        hipLaunchKernelGGL(mlp_mfma_kernel, dim3(mblocks), dim3(256), 0, stream,
                           pos, (const unsigned*)feat, W0, W1, W2, W3, out, n, nchunks);
    } else if (ws_size >= feat_bytes) {
        __hip_bfloat162* feat = (__hip_bfloat162*)d_ws;
        hipLaunchKernelGGL(hash_encode_kernel, dim3(16 * bpl), dim3(256), 0, stream,
                           pos, table, feat, n, bpl);
        hipLaunchKernelGGL(mlp_mfma_kernel, dim3(mblocks), dim3(256), 0, stream,
                           pos, (const unsigned*)feat, W0, W1, W2, W3, out, n, nchunks);
    } else {
        hipLaunchKernelGGL(hashgrid_fused_kernel, dim3(bpl), dim3(256), 0, stream,
                           pos, table, W0, W1, W2, W3, out, n);
    }
}

// Round 13
// 176.372 us; speedup vs baseline: 1.0255x; 1.0255x over previous
//
#include <hip/hip_runtime.h>
#include <hip/hip_bf16.h>

#define NLEV 16
#define TSIZE (1u << 19)
#define TMASK ((1u << 19) - 1u)
#define P1 2654435761u
#define P2 805459861u
#define FP8_SCALE 8192.0f
#define FP8_INV (1.0f / 8192.0f)

// Dense-grid tables for levels 0..3 (res 16,23,33,48): CDIM = R+2 cells/dim.
// (Level 4 tried in round 12: 6MB > 4MB L2 slice -> regression. Keep 0..3.)
#define NDENSE 4
#define DTOTAL 189332   // 18^3 + 25^3 + 35^3 + 50^3
#define CONV_BLOCKS 2048

typedef __attribute__((ext_vector_type(8))) short short8;
typedef __attribute__((ext_vector_type(4))) float f32x4;

// floor(16 * b^l), b = 256^(1/15) — matches numpy float64 computation.
__device__ __constant__ float c_res[NLEV] = {
    16.f, 23.f, 33.f, 48.f, 70.f, 101.f, 147.f, 212.f,
    307.f, 445.f, 645.f, 933.f, 1351.f, 1955.f, 2830.f, 4096.f};

__device__ __constant__ int c_cdim[NDENSE] = {18, 25, 35, 50};
__device__ __constant__ int c_doff[NDENSE] = {0, 5832, 21457, 64332}; // cell offsets

__device__ __forceinline__ short bf16_bits(float v) {
    __hip_bfloat16 h = __float2bfloat16(v);
    unsigned short us;
    __builtin_memcpy(&us, &h, 2);
    return (short)us;
}

__device__ __forceinline__ unsigned pack2_bf16(float lo, float hi) {
    unsigned a = (unsigned short)bf16_bits(lo);
    unsigned b = (unsigned short)bf16_bits(hi);
    return a | (b << 16);
}

// ---------------- Phase 0 (merged): convert fp8 pairs + build dense --------
// Blocks [0, CONV_BLOCKS): fp8 pair table for levels 4..15 (grid-stride).
// Blocks [CONV_BLOCKS, ...): dense 16B/cell tables for levels 0..3.
__global__ __launch_bounds__(256) void prep_kernel(
    const float2* __restrict__ table, unsigned* __restrict__ pq,
    uint4* __restrict__ dense, int conv_start, int conv_total)
{
    int b = blockIdx.x;
    if (b < CONV_BLOCKS) {
        for (int i = b * 256 + threadIdx.x; i < conv_total; i += CONV_BLOCKS * 256) {
            int ig = conv_start + i;
            float2 e = table[ig];
            float nx = __shfl_xor(e.x, 1);   // entry[ig^1] from partner lane
            float ny = __shfl_xor(e.y, 1);
            unsigned lo = __builtin_amdgcn_cvt_pk_fp8_f32(e.x * FP8_SCALE, e.y * FP8_SCALE, 0u, false);
            unsigned all4 = __builtin_amdgcn_cvt_pk_fp8_f32(nx * FP8_SCALE, ny * FP8_SCALE, lo, true);
            pq[ig] = all4;
        }
        return;
    }

    int t = (b - CONV_BLOCKS) * 256 + threadIdx.x;
    if (t >= DTOTAL) return;
    int l = 3;
    if (t < c_doff[1]) l = 0;
    else if (t < c_doff[2]) l = 1;
    else if (t < c_doff[3]) l = 2;
    int rel = t - c_doff[l];
    int dim = c_cdim[l];
    int ix = rel % dim;
    int rem = rel / dim;
    int iy = rem % dim;
    int iz = rem / dim;
    const float2* tl = table + (size_t)l * TSIZE;

    float2 v[8];
#pragma unroll
    for (int e = 0; e < 8; ++e) {
        unsigned cx = (unsigned)(ix + (e & 1));
        unsigned cy = (unsigned)(iy + ((e >> 1) & 1));
        unsigned cz = (unsigned)(iz + (e >> 2));
        unsigned h = (cx ^ (cy * P1) ^ (cz * P2)) & TMASK;
        v[e] = tl[h];
    }
    unsigned w[4];
#pragma unroll
    for (int d = 0; d < 4; ++d) {
        unsigned lo = __builtin_amdgcn_cvt_pk_fp8_f32(v[2 * d].x * FP8_SCALE,
                                                      v[2 * d].y * FP8_SCALE, 0u, false);
        w[d] = __builtin_amdgcn_cvt_pk_fp8_f32(v[2 * d + 1].x * FP8_SCALE,
                                               v[2 * d + 1].y * FP8_SCALE, lo, true);
    }
    dense[t] = make_uint4(w[0], w[1], w[2], w[3]);
}

// ---------------- Phase 1 (merged): hash levels 4..15 + dense levels 0..3 --
// Round-11 layout (best): 24 hash half-level units on 8 XCD slots (3 seq
// units/slot, one 2MB fp8 slice L2-resident per XCD); dense appended after.
__global__ __launch_bounds__(256) void encode_kernel(
    const float* __restrict__ pos,      // [N,3]
    const unsigned* __restrict__ pq,    // [16][2^19] fp8 pair (4..15 filled)
    const uint4* __restrict__ dense,    // dense cell tables, levels 0..3
    __hip_bfloat162* __restrict__ feat, // [16][N] level-major
    int n, unsigned halfn, unsigned nbh, unsigned bpl)
{
    unsigned b = blockIdx.x;
    unsigned H = 24u * nbh;
    const int tid = threadIdx.x;

    if (b >= H) {
        // ---- dense path ----
        unsigned db = b - H;
        int l = (int)(db / bpl);
        int i = (int)((db % bpl) * 256u) + tid;
        if (i >= n) return;

        float x = (pos[3 * i + 0] + 1.f) * 0.5f;
        float y = (pos[3 * i + 1] + 1.f) * 0.5f;
        float z = (pos[3 * i + 2] + 1.f) * 0.5f;
        float r = c_res[l];
        float sx = x * r, sy = y * r, sz = z * r;
        float fx = floorf(sx), fy = floorf(sy), fz = floorf(sz);
        float wx = sx - fx, wy = sy - fy, wz = sz - fz;
        int dim = c_cdim[l];
        unsigned ix = (unsigned)fx, iy = (unsigned)fy, iz = (unsigned)fz;
        ix = ix > (unsigned)(dim - 2) ? (unsigned)(dim - 2) : ix;
        iy = iy > (unsigned)(dim - 2) ? (unsigned)(dim - 2) : iy;
        iz = iz > (unsigned)(dim - 2) ? (unsigned)(dim - 2) : iz;

        uint4 wv = dense[(size_t)c_doff[l] + ((size_t)iz * dim + iy) * dim + ix];
        unsigned dw[4] = {wv.x, wv.y, wv.z, wv.w};

        float ux = 1.f - wx, uy = 1.f - wy, uz = 1.f - wz;
        float wyz[4] = {uy * uz, wy * uz, uy * wz, wy * wz};   // d = dy + 2*dz

        float f0 = 0.f, f1 = 0.f;
#pragma unroll
        for (int d = 0; d < 4; ++d) {
            unsigned word = dw[d];
            float we = ux * wyz[d];          // entry 2d   (dx=0): bytes 0,1
            float wo = wx * wyz[d];          // entry 2d+1 (dx=1): bytes 2,3
            f0 += __builtin_amdgcn_cvt_f32_fp8(word, 0) * we
                + __builtin_amdgcn_cvt_f32_fp8(word, 2) * wo;
            f1 += __builtin_amdgcn_cvt_f32_fp8(word, 1) * we
                + __builtin_amdgcn_cvt_f32_fp8(word, 3) * wo;
        }

        __hip_bfloat162 v;
        v.x = __float2bfloat16(f0 * FP8_INV);
        v.y = __float2bfloat16(f1 * FP8_INV);
        feat[(size_t)l * n + i] = v;
        return;
    }

    // ---- hash path ----
    unsigned slot = b & 7u;
    unsigned jj = b >> 3u;
    unsigned ur = jj / nbh;              // 0..2
    unsigned pb = jj % nbh;
    unsigned u = slot + 8u * ur;         // 0..23
    unsigned l = 4u + (u >> 1);
    unsigned half = u & 1u;
    const float r = c_res[l];
    const unsigned* tl = pq + (size_t)l * TSIZE;
    const int base = (int)(half * halfn + pb * 1024u);

    unsigned gq[16];
    float wxl[4], wyl[4], wzl[4];
    unsigned sll[4];
    int idx[4];

#pragma unroll
    for (int k = 0; k < 4; ++k) {
        int i = base + 256 * k + tid;
        if (i >= n) i = n - 1;           // clamp: harmless duplicate work
        idx[k] = i;
        float x = (pos[3 * i + 0] + 1.f) * 0.5f;
        float y = (pos[3 * i + 1] + 1.f) * 0.5f;
        float z = (pos[3 * i + 2] + 1.f) * 0.5f;
        float sx = x * r, sy = y * r, sz = z * r;
        float fx = floorf(sx), fy = floorf(sy), fz = floorf(sz);
        wxl[k] = sx - fx; wyl[k] = sy - fy; wzl[k] = sz - fz;
        unsigned ix = (unsigned)fx, iy = (unsigned)fy, iz = (unsigned)fz;
        unsigned hy0 = iy * P1, hy1 = hy0 + P1;
        unsigned hz0 = iz * P2, hz1 = hz0 + P2;
        unsigned a00 = hy0 ^ hz0, a10 = hy1 ^ hz0;
        unsigned a01 = hy0 ^ hz1, a11 = hy1 ^ hz1;
        unsigned sel = ix & 1u;
        unsigned jx = ix + sel;
        sll[k] = sel;
        gq[4 * k + 0] = tl[(jx ^ a00) & TMASK];
        gq[4 * k + 1] = tl[(jx ^ a10) & TMASK];
        gq[4 * k + 2] = tl[(jx ^ a01) & TMASK];
        gq[4 * k + 3] = tl[(jx ^ a11) & TMASK];
    }

#pragma unroll
    for (int k = 0; k < 4; ++k) {
        float wx = wxl[k], wy = wyl[k], wz = wzl[k];
        bool s = sll[k] != 0u;
        unsigned u00 = gq[4 * k + 0], u10 = gq[4 * k + 1];
        unsigned u01 = gq[4 * k + 2], u11 = gq[4 * k + 3];

        float a0_00 = __builtin_amdgcn_cvt_f32_fp8(u00, 0), a1_00 = __builtin_amdgcn_cvt_f32_fp8(u00, 1);
        float b0_00 = __builtin_amdgcn_cvt_f32_fp8(u00, 2), b1_00 = __builtin_amdgcn_cvt_f32_fp8(u00, 3);
        float a0_10 = __builtin_amdgcn_cvt_f32_fp8(u10, 0), a1_10 = __builtin_amdgcn_cvt_f32_fp8(u10, 1);
        float b0_10 = __builtin_amdgcn_cvt_f32_fp8(u10, 2), b1_10 = __builtin_amdgcn_cvt_f32_fp8(u10, 3);
        float a0_01 = __builtin_amdgcn_cvt_f32_fp8(u01, 0), a1_01 = __builtin_amdgcn_cvt_f32_fp8(u01, 1);
        float b0_01 = __builtin_amdgcn_cvt_f32_fp8(u01, 2), b1_01 = __builtin_amdgcn_cvt_f32_fp8(u01, 3);
        float a0_11 = __builtin_amdgcn_cvt_f32_fp8(u11, 0), a1_11 = __builtin_amdgcn_cvt_f32_fp8(u11, 1);
        float b0_11 = __builtin_amdgcn_cvt_f32_fp8(u11, 2), b1_11 = __builtin_amdgcn_cvt_f32_fp8(u11, 3);

        float lo0_00 = s ? b0_00 : a0_00, hi0_00 = s ? a0_00 : b0_00;
        float lo1_00 = s ? b1_00 : a1_00, hi1_00 = s ? a1_00 : b1_00;
        float lo0_10 = s ? b0_10 : a0_10, hi0_10 = s ? a0_10 : b0_10;
        float lo1_10 = s ? b1_10 : a1_10, hi1_10 = s ? a1_10 : b1_10;
        float lo0_01 = s ? b0_01 : a0_01, hi0_01 = s ? a0_01 : b0_01;
        float lo1_01 = s ? b1_01 : a1_01, hi1_01 = s ? a1_01 : b1_01;
        float lo0_11 = s ? b0_11 : a0_11, hi0_11 = s ? a0_11 : b0_11;
        float lo1_11 = s ? b1_11 : a1_11, hi1_11 = s ? a1_11 : b1_11;

        float ux = 1.f - wx, uy = 1.f - wy, uz = 1.f - wz;
        float w000 = ux * uy * uz, w100 = wx * uy * uz;
        float w010 = ux * wy * uz, w110 = wx * wy * uz;
        float w001 = ux * uy * wz, w101 = wx * uy * wz;
        float w011 = ux * wy * wz, w111 = wx * wy * wz;

        float f0 = lo0_00 * w000 + hi0_00 * w100 + lo0_10 * w010 + hi0_10 * w110 +
                   lo0_01 * w001 + hi0_01 * w101 + lo0_11 * w011 + hi0_11 * w111;
        float f1 = lo1_00 * w000 + hi1_00 * w100 + lo1_10 * w010 + hi1_10 * w110 +
                   lo1_01 * w001 + hi1_01 * w101 + lo1_11 * w011 + hi1_11 * w111;

        __hip_bfloat162 v;
        v.x = __float2bfloat16(f0 * FP8_INV);
        v.y = __float2bfloat16(f1 * FP8_INV);
        feat[(size_t)l * n + idx[k]] = v;
    }
}

// ---------------- Phase 1 fallback: fp32 table, 8 gathers, 16 levels -------
__global__ __launch_bounds__(256) void hash_encode_kernel(
    const float* __restrict__ pos,
    const float* __restrict__ table,
    __hip_bfloat162* __restrict__ feat,
    int n, unsigned bpl)
{
    unsigned b = blockIdx.x;
    unsigned slot = b & 7u;
    unsigned jj = b >> 3u;
    unsigned l = slot + 8u * (jj / bpl);
    unsigned pblk = jj % bpl;
    int i = (int)(pblk * 256u + threadIdx.x);
    if (i >= n) return;

    float x = (pos[3 * i + 0] + 1.f) * 0.5f;
    float y = (pos[3 * i + 1] + 1.f) * 0.5f;
    float z = (pos[3 * i + 2] + 1.f) * 0.5f;

    float r = c_res[l];
    float sx = x * r, sy = y * r, sz = z * r;
    float fx = floorf(sx), fy = floorf(sy), fz = floorf(sz);
    float wx = sx - fx, wy = sy - fy, wz = sz - fz;
    unsigned ix = (unsigned)fx, iy = (unsigned)fy, iz = (unsigned)fz;
    unsigned hy0 = iy * P1, hy1 = hy0 + P1;
    unsigned hz0 = iz * P2, hz1 = hz0 + P2;
    unsigned a00 = hy0 ^ hz0, a10 = hy1 ^ hz0;
    unsigned a01 = hy0 ^ hz1, a11 = hy1 ^ hz1;
    unsigned ix1 = ix + 1u;

    const float2* tl = (const float2*)table + (size_t)l * TSIZE;
    float2 e000 = tl[(ix  ^ a00) & TMASK];
    float2 e100 = tl[(ix1 ^ a00) & TMASK];
    float2 e010 = tl[(ix  ^ a10) & TMASK];
    float2 e110 = tl[(ix1 ^ a10) & TMASK];
    float2 e001 = tl[(ix  ^ a01) & TMASK];
    float2 e101 = tl[(ix1 ^ a01) & TMASK];
    float2 e011 = tl[(ix  ^ a11) & TMASK];
    float2 e111 = tl[(ix1 ^ a11) & TMASK];

    float ux = 1.f - wx, uy = 1.f - wy, uz = 1.f - wz;
    float w000 = ux * uy * uz, w100 = wx * uy * uz;
    float w010 = ux * wy * uz, w110 = wx * wy * uz;
    float w001 = ux * uy * wz, w101 = wx * uy * wz;
    float w011 = ux * wy * wz, w111 = wx * wy * wz;

    float f0 = e000.x * w000 + e100.x * w100 + e010.x * w010 + e110.x * w110 +
               e001.x * w001 + e101.x * w101 + e011.x * w011 + e111.x * w111;
    float f1 = e000.y * w000 + e100.y * w100 + e010.y * w010 + e110.y * w110 +
               e001.y * w001 + e101.y * w101 + e011.y * w011 + e111.y * w111;

    __hip_bfloat162 v;
    v.x = __float2bfloat16(f0);
    v.y = __float2bfloat16(f1);
    feat[(size_t)l * n + i] = v;
}

// ---------------- Phase 2: bf16 MFMA MLP (t-parity double-buffered LDS) ----
__device__ __forceinline__ void store_H(char* hrow, int g, int swz, f32x4* acc) {
#pragma unroll
    for (int mt = 0; mt < 4; ++mt) {
        float v0 = fmaxf(acc[mt][0], 0.f), v1 = fmaxf(acc[mt][1], 0.f);
        float v2 = fmaxf(acc[mt][2], 0.f), v3 = fmaxf(acc[mt][3], 0.f);
        unsigned lo = pack2_bf16(v0, v1);
        unsigned hi = pack2_bf16(v2, v3);
        int blk = (2 * mt + (g >> 1)) ^ swz;
        *(uint2*)(hrow + blk * 16 + (g & 1) * 8) = make_uint2(lo, hi);
    }
}

__global__ __launch_bounds__(256) void mlp_mfma_kernel(
    const float* __restrict__ pos,
    const unsigned* __restrict__ feat,  // [16][n] u32 = bf16x2
    const float* __restrict__ W0,
    const float* __restrict__ W1,
    const float* __restrict__ W2,
    const float* __restrict__ W3,
    float* __restrict__ out, int n, int nchunks)
{
    __shared__ char hlds[2 * 4 * 16 * 128];   // [t-parity][wave][16 rows][128B]
    const int tid  = threadIdx.x;
    const int w    = tid >> 6;
    const int lane = tid & 63;
    const int g    = lane >> 4;
    const int p    = lane & 15;
    const int swz = p & 7;

    short8 a0[4], a1[4][2], a2[4][2], a3[2];
#pragma unroll
    for (int mt = 0; mt < 4; ++mt)
#pragma unroll
        for (int jj = 0; jj < 8; ++jj)
            a0[mt][jj] = bf16_bits(W0[(8 * g + jj) * 64 + 16 * mt + p]);
#pragma unroll
    for (int mt = 0; mt < 4; ++mt)
#pragma unroll
        for (int kt = 0; kt < 2; ++kt)
#pragma unroll
            for (int jj = 0; jj < 8; ++jj) {
                a1[mt][kt][jj] = bf16_bits(W1[(32 * kt + 8 * g + jj) * 64 + 16 * mt + p]);
                a2[mt][kt][jj] = bf16_bits(W2[(32 * kt + 8 * g + jj) * 64 + 16 * mt + p]);
            }
#pragma unroll
    for (int kt = 0; kt < 2; ++kt)
#pragma unroll
        for (int jj = 0; jj < 8; ++jj)
            a3[kt][jj] = (p < 4) ? bf16_bits(W3[(32 * kt + 8 * g + jj) * 4 + p]) : (short)0;

    const f32x4 zf = {0.f, 0.f, 0.f, 0.f};

    for (int c = blockIdx.x; c < nchunks; c += gridDim.x) {
        const int base = c * 256 + w * 64;

        // batch all 16 feat loads (4 t-tiles x 4 planes) before any compute
        unsigned buall[4][4];
#pragma unroll
        for (int t = 0; t < 4; ++t) {
            int ptg = base + t * 16 + p;
            int ptc = ptg < n ? ptg : n - 1;
#pragma unroll
            for (int m = 0; m < 4; ++m)
                buall[t][m] = feat[(size_t)(4 * g + m) * (size_t)n + ptc];
        }

#pragma unroll
        for (int t = 0; t < 4; ++t) {
            const int ptg = base + t * 16 + p;
            // t-parity double buffer: breaks the WAR hazard between
            // consecutive t-iterations so two chains can overlap.
            char* hrow = hlds + (t & 1) * 8192 + w * 2048 + p * 128;

            union { unsigned u[4]; short8 s; } bu;
#pragma unroll
            for (int m = 0; m < 4; ++m) bu.u[m] = buall[t][m];

            f32x4 acc[4];
#pragma unroll
            for (int mt = 0; mt < 4; ++mt)
                acc[mt] = __builtin_amdgcn_mfma_f32_16x16x32_bf16(a0[mt], bu.s, zf, 0, 0, 0);

            store_H(hrow, g, swz, acc);
            short8 b0 = *(const short8*)(hrow + ((g ^ swz) << 4));
            short8 b1 = *(const short8*)(hrow + (((4 + g) ^ swz) << 4));

#pragma unroll
            for (int mt = 0; mt < 4; ++mt) {
                acc[mt] = __builtin_amdgcn_mfma_f32_16x16x32_bf16(a1[mt][0], b0, zf, 0, 0, 0);
                acc[mt] = __builtin_amdgcn_mfma_f32_16x16x32_bf16(a1[mt][1], b1, acc[mt], 0, 0, 0);
            }

            store_H(hrow, g, swz, acc);
            b0 = *(const short8*)(hrow + ((g ^ swz) << 4));
            b1 = *(const short8*)(hrow + (((4 + g) ^ swz) << 4));

#pragma unroll
            for (int mt = 0; mt < 4; ++mt) {
                acc[mt] = __builtin_amdgcn_mfma_f32_16x16x32_bf16(a2[mt][0], b0, zf, 0, 0, 0);
                acc[mt] = __builtin_amdgcn_mfma_f32_16x16x32_bf16(a2[mt][1], b1, acc[mt], 0, 0, 0);
            }

            store_H(hrow, g, swz, acc);
            b0 = *(const short8*)(hrow + ((g ^ swz) << 4));
            b1 = *(const short8*)(hrow + (((4 + g) ^ swz) << 4));

            f32x4 o = __builtin_amdgcn_mfma_f32_16x16x32_bf16(a3[0], b0, zf, 0, 0, 0);
            o = __builtin_amdgcn_mfma_f32_16x16x32_bf16(a3[1], b1, o, 0, 0, 0);

            if (g == 0 && ptg < n) {
                float px = pos[3 * ptg + 0];
                float py = pos[3 * ptg + 1];
                float pz = pos[3 * ptg + 2];
                float xx = (px + 1.f) * 0.5f;
                float yy = (py + 1.f) * 0.5f;
                float zz = (pz + 1.f) * 0.5f;
                bool sel = (xx > 0.f) && (xx < 1.f) && (yy > 0.f) && (yy < 1.f) &&
                           (zz > 0.f) && (zz < 1.f);
                out[3 * (size_t)ptg + 0] = 1.f / (1.f + expf(-o[0]));
                out[3 * (size_t)ptg + 1] = 1.f / (1.f + expf(-o[1]));
                out[3 * (size_t)ptg + 2] = 1.f / (1.f + expf(-o[2]));
                out[3 * (size_t)n + ptg] = expf(o[3] - 1.f) * (sel ? 1.f : 0.f);
            }
        }
    }
}

// ---------------- Fallback: fused scalar kernel (if ws too small) ----------
__global__ __launch_bounds__(256) void hashgrid_fused_kernel(
    const float* __restrict__ pos, const float* __restrict__ table,
    const float* __restrict__ W0, const float* __restrict__ W1,
    const float* __restrict__ W2, const float* __restrict__ W3,
    float* __restrict__ out, int n)
{
    int id = blockIdx.x * 256 + threadIdx.x;
    int i = id < n ? id : n - 1;

    float x = (pos[3 * i + 0] + 1.f) * 0.5f;
    float y = (pos[3 * i + 1] + 1.f) * 0.5f;
    float z = (pos[3 * i + 2] + 1.f) * 0.5f;
    bool sel = (x > 0.f) && (x < 1.f) && (y > 0.f) && (y < 1.f) &&
               (z > 0.f) && (z < 1.f);

    float h0[64];
#pragma unroll
    for (int j = 0; j < 64; ++j) h0[j] = 0.f;

    const float2* tb = (const float2*)table;
#pragma unroll
    for (int l = 0; l < NLEV; ++l) {
        float r = c_res[l];
        float sx = x * r, sy = y * r, sz = z * r;
        float fx = floorf(sx), fy = floorf(sy), fz = floorf(sz);
        float wx = sx - fx, wy = sy - fy, wz = sz - fz;
        unsigned ix = (unsigned)fx, iy = (unsigned)fy, iz = (unsigned)fz;
        unsigned hy0 = iy * P1, hy1 = hy0 + P1;
        unsigned hz0 = iz * P2, hz1 = hz0 + P2;
        unsigned a00 = hy0 ^ hz0, a10 = hy1 ^ hz0;
        unsigned a01 = hy0 ^ hz1, a11 = hy1 ^ hz1;
        unsigned ix1 = ix + 1u;
        const float2* tl = tb + (size_t)l * TSIZE;
        float2 e000 = tl[(ix  ^ a00) & TMASK];
        float2 e100 = tl[(ix1 ^ a00) & TMASK];
        float2 e010 = tl[(ix  ^ a10) & TMASK];
        float2 e110 = tl[(ix1 ^ a10) & TMASK];
        float2 e001 = tl[(ix  ^ a01) & TMASK];
        float2 e101 = tl[(ix1 ^ a01) & TMASK];
        float2 e011 = tl[(ix  ^ a11) & TMASK];
        float2 e111 = tl[(ix1 ^ a11) & TMASK];

        float ux = 1.f - wx, uy = 1.f - wy, uz = 1.f - wz;
        float w000 = ux * uy * uz, w100 = wx * uy * uz;
        float w010 = ux * wy * uz, w110 = wx * wy * uz;
        float w001 = ux * uy * wz, w101 = wx * uy * wz;
        float w011 = ux * wy * wz, w111 = wx * wy * wz;

        float f0 = e000.x * w000 + e100.x * w100 + e010.x * w010 + e110.x * w110 +
                   e001.x * w001 + e101.x * w101 + e011.x * w011 + e111.x * w111;
        float f1 = e000.y * w000 + e100.y * w100 + e010.y * w010 + e110.y * w110 +
                   e001.y * w001 + e101.y * w101 + e011.y * w011 + e111.y * w111;

        const float* w0a = W0 + (2 * l) * 64;
        const float* w0b = W0 + (2 * l + 1) * 64;
#pragma unroll
        for (int j = 0; j < 64; ++j)
            h0[j] = fmaf(f0, w0a[j], fmaf(f1, w0b[j], h0[j]));
    }
#pragma unroll
    for (int j = 0; j < 64; ++j) h0[j] = fmaxf(h0[j], 0.f);

    float h1[64];
#pragma unroll
    for (int j = 0; j < 64; ++j) h1[j] = 0.f;
#pragma unroll
    for (int k = 0; k < 64; ++k) {
        float v = h0[k];
        const float* wr = W1 + k * 64;
#pragma unroll
        for (int j = 0; j < 64; ++j) h1[j] = fmaf(v, wr[j], h1[j]);
    }
#pragma unroll
    for (int j = 0; j < 64; ++j) h1[j] = fmaxf(h1[j], 0.f);

#pragma unroll
    for (int j = 0; j < 64; ++j) h0[j] = 0.f;
#pragma unroll
    for (int k = 0; k < 64; ++k) {
        float v = h1[k];
        const float* wr = W2 + k * 64;
#pragma unroll
        for (int j = 0; j < 64; ++j) h0[j] = fmaf(v, wr[j], h0[j]);
    }
#pragma unroll
    for (int j = 0; j < 64; ++j) h0[j] = fmaxf(h0[j], 0.f);

    float o0 = 0.f, o1 = 0.f, o2 = 0.f, o3 = 0.f;
#pragma unroll
    for (int k = 0; k < 64; ++k) {
        float v = h0[k];
        const float* wr = W3 + k * 4;
        o0 = fmaf(v, wr[0], o0);
        o1 = fmaf(v, wr[1], o1);
        o2 = fmaf(v, wr[2], o2);
        o3 = fmaf(v, wr[3], o3);
    }

    if (id < n) {
        float r = 1.f / (1.f + expf(-o0));
        float g = 1.f / (1.f + expf(-o1));
        float b = 1.f / (1.f + expf(-o2));
        float d = expf(o3 - 1.f) * (sel ? 1.f : 0.f);
        out[3 * (size_t)i + 0] = r;
        out[3 * (size_t)i + 1] = g;
        out[3 * (size_t)i + 2] = b;
        out[3 * (size_t)n + i] = d;
    }
}

extern "C" void kernel_launch(void* const* d_in, const int* in_sizes, int n_in,
                              void* d_out, int out_size, void* d_ws, size_t ws_size,
                              hipStream_t stream) {
    const float* pos   = (const float*)d_in[0];
    const float* table = (const float*)d_in[1];
    const float* W0    = (const float*)d_in[2];
    const float* W1    = (const float*)d_in[3];
    const float* W2    = (const float*)d_in[4];
    const float* W3    = (const float*)d_in[5];
    float* out = (float*)d_out;
    int n = in_sizes[0] / 3;
    unsigned bpl = (unsigned)((n + 255) / 256);
    unsigned halfn = (unsigned)((n + 1) / 2);
    unsigned nbh = (halfn + 1023) / 1024;
    int nchunks = (n + 255) / 256;
    int mblocks = nchunks < 2048 ? nchunks : 2048;

    size_t pq_bytes    = (size_t)NLEV * TSIZE * sizeof(unsigned);  // 33.5 MB
    size_t dense_bytes = (size_t)DTOTAL * sizeof(uint4);           // 3.03 MB
    size_t feat_bytes  = (size_t)NLEV * n * sizeof(__hip_bfloat162);

    if (ws_size >= pq_bytes + dense_bytes + feat_bytes) {
        unsigned* pq = (unsigned*)d_ws;
        uint4* dense = (uint4*)((char*)d_ws + pq_bytes);
        __hip_bfloat162* feat = (__hip_bfloat162*)((char*)d_ws + pq_bytes + dense_bytes);

        int prep_blocks = CONV_BLOCKS + (DTOTAL + 255) / 256;
        hipLaunchKernelGGL(prep_kernel, dim3(prep_blocks), dim3(256), 0, stream,
                           (const float2*)table, pq, dense,
                           4 * (int)TSIZE, 12 * (int)TSIZE);
        unsigned enc_blocks = 24u * nbh + NDENSE * bpl;
        hipLaunchKernelGGL(encode_kernel, dim3(enc_blocks), dim3(256), 0, stream,
                           pos, pq, dense, feat, n, halfn, nbh, bpl);
        hipLaunchKernelGGL(mlp_mfma_kernel, dim3(mblocks), dim3(256), 0, stream,
                           pos, (const unsigned*)feat, W0, W1, W2, W3, out, n, nchunks);
    } else if (ws_size >= feat_bytes) {
        __hip_bfloat162* feat = (__hip_bfloat162*)d_ws;
        hipLaunchKernelGGL(hash_encode_kernel, dim3(16 * bpl), dim3(256), 0, stream,
                           pos, table, feat, n, bpl);
        hipLaunchKernelGGL(mlp_mfma_kernel, dim3(mblocks), dim3(256), 0, stream,
                           pos, (const unsigned*)feat, W0, W1, W2, W3, out, n, nchunks);
    } else {
        hipLaunchKernelGGL(hashgrid_fused_kernel, dim3(bpl), dim3(256), 0, stream,
                           pos, table, W0, W1, W2, W3, out, n);
    }
}